// Round 10
// baseline (392.725 us; speedup 1.0000x reference)
//
#include <hip/hip_runtime.h>

// CorrNeigh: out[b, i*7+j, h, w] = sum_c x[b,c,h,w] * y[b,c,h+i-3,w+j-3]
// B=8 C=128 H=W=256, K=7, PAD=3, fp32.
//
// Round 10: R9 still spilled (~200MB scratch, VGPR=64) because min-only
// waves_per_eu(4) leaves the occupancy target unbounded -> allocator chases
// 8 waves/EU. Fix: amdgpu_waves_per_eu(3,4) — bounded range: budget >=170,
// occupancy target capped at 4/EU. Plus: 8-slot ring / prefetch-6 /
// steady-state vmcnt(4) (retires exactly the 2 channels consumed per iter;
// ~2.5 iterations of flight time > 900cy HBM latency).
//
// Slot layout (7168B = 448 thread-chunks, 1 DMA instr/wave/channel):
//   y: 14 rows x 21 chunks, pitch 84 floats -> b128 reads hit all 32 banks
//     uniformly (8 words/bank = minimum)
//   x:  8 rows x 17 chunks, pitch 68 floats -> same
//   pad/oob chunks -> zbuf (stride 0) = zeros.
// Ring safety: slot for ch c+8 is overwritten by a DMA issued AFTER the
// barrier at iter (c+2)/2... i.e. one iteration after ch c's ds_reads were
// drained by lgkmcnt(0)+barrier. Every wave waits its own vmcnt before the
// barrier, so after the barrier all 448 chunks of the needed slots landed.

#define Bq 8
#define Cq 128
#define Hq 256
#define Wq 256
#define Kq 7
#define TILE_H 8
#define TILE_W 64
#define NTHR 448
#define CS (Hq * Wq)
#define SLOT 7168
#define NSLOT 8
#define RING (NSLOT * SLOT)
#define YPITCH_B 336   // 84 floats
#define XBASE_B  4704  // 294 chunks * 16B
#define XPITCH_B 272   // 68 floats

typedef const __attribute__((address_space(1))) void* gptr_t;
typedef __attribute__((address_space(3))) void* lptr_t;

__device__ __forceinline__ void dma16(const float* g, char* l) {
    __builtin_amdgcn_global_load_lds((gptr_t)g, (lptr_t)l, 16, 0, 0);
}

__global__ __launch_bounds__(NTHR)
__attribute__((amdgpu_waves_per_eu(3, 4)))
void corr7_kernel(const float* __restrict__ x, const float* __restrict__ y,
                  float* __restrict__ out, const float* __restrict__ zbuf)
{
    __shared__ __align__(16) char smem[RING];

    const int t    = threadIdx.x;
    const int wave = t >> 6;        // dy index (0..6)
    const int lane = t & 63;
    const int lw   = lane & 7;      // w-octet
    const int lr   = lane >> 3;     // row in tile (0..7)

    // XCD-chunked swizzle: XCD k gets tiles [k*128,(k+1)*128) = one image
    int bid = (int)blockIdx.x;
    bid = (bid & 7) * 128 + (bid >> 3);
    const int tw = bid & 3;
    const int th = (bid >> 2) & 31;
    const int b  = bid >> 7;

    const int h0 = th * TILE_H;
    const int w0 = tw * TILE_W;
    const int wq = w0 + 8 * lw;

    const size_t base = (size_t)b * Cq * CS;

    // ---- staging role: thread t DMAs 16B chunk #t of each slot ----
    const float* src;
    unsigned sstep;
    {
        if (t < 294) {                        // y: 14 rows x 21 chunks
            const int r = t / 21, j = t - 21 * r;
            const int gy = h0 + r - 3;
            const int gx = w0 - 8 + 4 * j;    // chunk covers gx..gx+3
            const bool v = (j < 20) && ((unsigned)gy < (unsigned)Hq) &&
                           (gx >= 0) && (gx + 3 < Wq);
            src   = v ? (y + base + (size_t)gy * Wq + gx) : zbuf;
            sstep = v ? (unsigned)CS : 0u;
        } else if (t < 430) {                 // x: 8 rows x 17 chunks
            const int u = t - 294;
            const int r = u / 17, j = u - 17 * r;
            const bool v = (j < 16);
            src   = v ? (x + base + (size_t)(h0 + r) * Wq + (w0 + 4 * j)) : zbuf;
            sstep = v ? (unsigned)CS : 0u;
        } else {                              // filler
            src   = zbuf;
            sstep = 0u;
        }
    }

    // ---- compute-role LDS byte offsets (within a slot) ----
    // y window: row R=lr+wave, words 8lw+4..8lw+19 (uses 5..18 = wq-3..wq+10)
    const int yb = (lr + wave) * YPITCH_B + 32 * lw + 16;
    const int xb = XBASE_B + lr * XPITCH_B + 32 * lw;

    float acc[Kq][8];
#pragma unroll
    for (int j = 0; j < Kq; ++j)
#pragma unroll
        for (int r = 0; r < 8; ++r) acc[j][r] = 0.f;

#define COMPUTE(OFF) {                                                    \
    const char* sr = (const char*)smem + (OFF);                           \
    const float4 q0 = *(const float4*)(sr + yb);                          \
    const float4 q1 = *(const float4*)(sr + yb + 16);                     \
    const float4 q2 = *(const float4*)(sr + yb + 32);                     \
    const float4 q3 = *(const float4*)(sr + yb + 48);                     \
    const float4 p0 = *(const float4*)(sr + xb);                          \
    const float4 p1 = *(const float4*)(sr + xb + 16);                     \
    float yf[16];                                                         \
    *(float4*)(yf)      = q0;  *(float4*)(yf + 4)  = q1;                  \
    *(float4*)(yf + 8)  = q2;  *(float4*)(yf + 12) = q3;                  \
    float xv[8];                                                          \
    *(float4*)(xv)      = p0;  *(float4*)(xv + 4)  = p1;                  \
    _Pragma("unroll")                                                     \
    for (int j = 0; j < Kq; ++j)                                          \
        _Pragma("unroll")                                                 \
        for (int r = 0; r < 8; ++r)                                       \
            acc[j][r] = fmaf(xv[r], yf[1 + j + r], acc[j][r]);            \
}

    // prologue: DMA channels 0..5 into slots 0..5
#pragma unroll
    for (int c = 0; c < 6; ++c) {
        dma16(src, smem + c * SLOT + t * 16);
        src += sstep;
    }

    unsigned rd = 0;
    unsigned wr = 6u * SLOT;
    // steady state: iters k=0..60 compute ch 2k,2k+1, issue ch 2k+6,2k+7.
    // At iter-k top, outstanding = ch 2k..2k+5 (6); vmcnt(4) retires exactly
    // ch 2k,2k+1.
#pragma unroll 1
    for (int k = 0; k < 61; ++k) {
        asm volatile("s_waitcnt vmcnt(4) lgkmcnt(0)" ::: "memory");
        __builtin_amdgcn_s_barrier();
        dma16(src, smem + wr + t * 16); src += sstep;
        wr += SLOT; if (wr == RING) wr = 0;
        dma16(src, smem + wr + t * 16); src += sstep;
        wr += SLOT; if (wr == RING) wr = 0;
        COMPUTE(rd)
        rd += SLOT; if (rd == RING) rd = 0;
        COMPUTE(rd)
        rd += SLOT; if (rd == RING) rd = 0;
    }
    // drain: ch 122..127 (outstanding 6 -> 4 -> 2 -> 0)
    {
        asm volatile("s_waitcnt vmcnt(4) lgkmcnt(0)" ::: "memory");
        __builtin_amdgcn_s_barrier();
        COMPUTE(rd) rd += SLOT; if (rd == RING) rd = 0;
        COMPUTE(rd) rd += SLOT; if (rd == RING) rd = 0;

        asm volatile("s_waitcnt vmcnt(2) lgkmcnt(0)" ::: "memory");
        __builtin_amdgcn_s_barrier();
        COMPUTE(rd) rd += SLOT; if (rd == RING) rd = 0;
        COMPUTE(rd) rd += SLOT; if (rd == RING) rd = 0;

        asm volatile("s_waitcnt vmcnt(0) lgkmcnt(0)" ::: "memory");
        __builtin_amdgcn_s_barrier();
        COMPUTE(rd) rd += SLOT; if (rd == RING) rd = 0;
        COMPUTE(rd)
    }
#undef COMPUTE

    // epilogue: wave writes k-planes wave*7 .. wave*7+6 (one octet each)
    size_t obase = (((size_t)b * (Kq * Kq) + (size_t)wave * Kq) * Hq
                    + (h0 + lr)) * Wq + wq;
#pragma unroll
    for (int j = 0; j < Kq; ++j) {
        float4 o0 = {acc[j][0], acc[j][1], acc[j][2], acc[j][3]};
        float4 o1 = {acc[j][4], acc[j][5], acc[j][6], acc[j][7]};
        *(float4*)(out + obase)     = o0;
        *(float4*)(out + obase + 4) = o1;
        obase += (size_t)CS;
    }
}

extern "C" void kernel_launch(void* const* d_in, const int* in_sizes, int n_in,
                              void* d_out, int out_size, void* d_ws, size_t ws_size,
                              hipStream_t stream) {
    const float* x = (const float*)d_in[0];
    const float* y = (const float*)d_in[1];
    float* out = (float*)d_out;

    // zero pad-source region (invalid/pad chunks aim here, stride 0)
    hipMemsetAsync(d_ws, 0, 256, stream);

    dim3 grid(Bq * 32 * 4);   // 1024 tiles: 8 b x 32 h x 4 w
    dim3 block(NTHR);
    hipLaunchKernelGGL(corr7_kernel, grid, block, 0, stream,
                       x, y, out, (const float*)d_ws);
}

// Round 11
// 337.728 us; speedup vs baseline: 1.1628x; 1.1628x over previous
//
#include <hip/hip_runtime.h>

// CorrNeigh: out[b, i*7+j, h, w] = sum_c x[b,c,h,w] * y[b,c,h+i-3,w+j-3]
// B=8 C=128 H=W=256, K=7, PAD=3, fp32.
//
// Round 11: LDS-pipe diet + register-demand diet on the R9 ring (best: 309us).
//  - x NO LONGER staged in LDS: each lane loads its x octet from global
//    (L1 serves the 7x dy-wave reuse). LDS reads/wave-channel: 6 -> 4 b128
//    (-33% on the binding pipe); slot = y-only 4704B; ring 28KB -> 4 blk/CU.
//  - vmem ISSUE ORDER: x loads at iteration top BEFORE the dma16s. vmcnt
//    retires in order, so consuming x only forces retirement of PREVIOUS
//    iterations' DMAs (= the vmcnt(2) semantics we want). x after the DMAs
//    would chain each iteration's FMAs to its own prefetch.
//  - Everything else proven in R8/R9: 6-slot ring, 2ch/barrier, vmcnt(2)
//    steady wait, pitch-84 y rows (uniform 8 words/bank for b128), pad via
//    zbuf pointer-redirect (stride 0), XCD-chunked swizzle, waves_per_eu(3,4).
// Ring safety (unchanged from R9): slot overwritten at iter k was read at
// iter k-1; reads drained by lgkmcnt(0)+barrier before the DMA issues; each
// producer wave waits ITS vmcnt before the barrier, so post-barrier all
// slot chunks have landed.

#define Bq 8
#define Cq 128
#define Hq 256
#define Wq 256
#define Kq 7
#define TILE_H 8
#define TILE_W 64
#define NTHR 448
#define CS (Hq * Wq)
#define SLOT 4704          // y-only: 14 rows x 21 chunks x 16B
#define NSLOT 6
#define RING (NSLOT * SLOT)
#define YPITCH_B 336       // 84 floats

typedef const __attribute__((address_space(1))) void* gptr_t;
typedef __attribute__((address_space(3))) void* lptr_t;

__device__ __forceinline__ void dma16(const float* g, char* l) {
    __builtin_amdgcn_global_load_lds((gptr_t)g, (lptr_t)l, 16, 0, 0);
}

__global__ __launch_bounds__(NTHR)
__attribute__((amdgpu_waves_per_eu(3, 4)))
void corr7_kernel(const float* __restrict__ x, const float* __restrict__ y,
                  float* __restrict__ out, const float* __restrict__ zbuf)
{
    __shared__ __align__(16) char smem[RING];

    const int t    = threadIdx.x;
    const int wave = t >> 6;        // dy index (0..6)
    const int lane = t & 63;
    const int lw   = lane & 7;      // w-octet
    const int lr   = lane >> 3;     // row in tile (0..7)

    // XCD-chunked swizzle: XCD k gets tiles [k*128,(k+1)*128) = one image
    int bid = (int)blockIdx.x;
    bid = (bid & 7) * 128 + (bid >> 3);
    const int tw = bid & 3;
    const int th = (bid >> 2) & 31;
    const int b  = bid >> 7;

    const int h0 = th * TILE_H;
    const int w0 = tw * TILE_W;
    const int wq = w0 + 8 * lw;

    const size_t base = (size_t)b * Cq * CS;

    // ---- staging role: threads 0..293 DMA one 16B y-chunk per channel ----
    const bool prod = (t < 294);
    const float* src;
    unsigned sstep;
    {
        const int r = t / 21, j = t - 21 * r;   // row 0..13, chunk 0..20
        const int gy = h0 + r - 3;
        const int gx = w0 - 8 + 4 * j;          // chunk covers gx..gx+3
        const bool v = prod && (j < 20) && ((unsigned)gy < (unsigned)Hq) &&
                       (gx >= 0) && (gx + 3 < Wq);
        src   = v ? (y + base + (size_t)gy * Wq + gx) : zbuf;
        sstep = v ? (unsigned)CS : 0u;
    }

    // ---- compute-role offsets ----
    // y window: row R=lr+wave, floats 8lw+4 .. 8lw+19 (window = idx 1..14)
    const int yb = (lr + wave) * YPITCH_B + 32 * lw + 16;
    const float* px = x + base + (size_t)(h0 + lr) * Wq + wq;

    float acc[Kq][8];
#pragma unroll
    for (int j = 0; j < Kq; ++j)
#pragma unroll
        for (int r = 0; r < 8; ++r) acc[j][r] = 0.f;

#define COMPUTE(OFF, X0, X1) {                                            \
    const char* sr = (const char*)smem + (OFF);                           \
    const float4 q0 = *(const float4*)(sr + yb);                          \
    const float4 q1 = *(const float4*)(sr + yb + 16);                     \
    const float4 q2 = *(const float4*)(sr + yb + 32);                     \
    const float4 q3 = *(const float4*)(sr + yb + 48);                     \
    float yf[16];                                                         \
    *(float4*)(yf)      = q0;  *(float4*)(yf + 4)  = q1;                  \
    *(float4*)(yf + 8)  = q2;  *(float4*)(yf + 12) = q3;                  \
    float xv[8];                                                          \
    *(float4*)(xv)      = X0;  *(float4*)(xv + 4)  = X1;                  \
    _Pragma("unroll")                                                     \
    for (int j = 0; j < Kq; ++j)                                          \
        _Pragma("unroll")                                                 \
        for (int r = 0; r < 8; ++r)                                       \
            acc[j][r] = fmaf(xv[r], yf[1 + j + r], acc[j][r]);            \
}

    // prologue: DMA channels 0..3 into slots 0..3
#pragma unroll
    for (int c = 0; c < 4; ++c) {
        if (prod) { dma16(src, smem + c * SLOT + t * 16); src += sstep; }
    }

    unsigned rd = 0;
    unsigned wr = 4u * SLOT;
    // steady: iter k computes ch 2k,2k+1; issues ch 2k+4,2k+5.
#pragma unroll 1
    for (int k = 0; k < 62; ++k) {
        asm volatile("s_waitcnt vmcnt(2) lgkmcnt(0)" ::: "memory");
        __builtin_amdgcn_s_barrier();
        // x octets for ch 2k (A) and 2k+1 (B) — issued BEFORE the DMAs
        const float4 xa0 = *(const float4*)(px);
        const float4 xa1 = *(const float4*)(px + 4);
        const float4 xb0 = *(const float4*)(px + CS);
        const float4 xb1 = *(const float4*)(px + CS + 4);
        px += 2 * CS;
        asm volatile("" ::: "memory");       // keep x-issue above DMA-issue
        if (prod) { dma16(src, smem + wr + t * 16); src += sstep; }
        wr += SLOT; if (wr == RING) wr = 0;
        if (prod) { dma16(src, smem + wr + t * 16); src += sstep; }
        wr += SLOT; if (wr == RING) wr = 0;
        COMPUTE(rd, xa0, xa1)
        rd += SLOT; if (rd == RING) rd = 0;
        COMPUTE(rd, xb0, xb1)
        rd += SLOT; if (rd == RING) rd = 0;
    }
    // drain: ch 124..127
    {
        asm volatile("s_waitcnt vmcnt(2) lgkmcnt(0)" ::: "memory");
        __builtin_amdgcn_s_barrier();
        const float4 xa0 = *(const float4*)(px);
        const float4 xa1 = *(const float4*)(px + 4);
        const float4 xb0 = *(const float4*)(px + CS);
        const float4 xb1 = *(const float4*)(px + CS + 4);
        px += 2 * CS;
        COMPUTE(rd, xa0, xa1)
        rd += SLOT; if (rd == RING) rd = 0;
        COMPUTE(rd, xb0, xb1)
        rd += SLOT; if (rd == RING) rd = 0;
    }
    {
        asm volatile("s_waitcnt vmcnt(0) lgkmcnt(0)" ::: "memory");
        __builtin_amdgcn_s_barrier();
        const float4 xa0 = *(const float4*)(px);
        const float4 xa1 = *(const float4*)(px + 4);
        const float4 xb0 = *(const float4*)(px + CS);
        const float4 xb1 = *(const float4*)(px + CS + 4);
        COMPUTE(rd, xa0, xa1)
        rd += SLOT; if (rd == RING) rd = 0;
        COMPUTE(rd, xb0, xb1)
    }
#undef COMPUTE

    // epilogue: wave writes k-planes wave*7 .. wave*7+6 (one octet each)
    size_t obase = (((size_t)b * (Kq * Kq) + (size_t)wave * Kq) * Hq
                    + (h0 + lr)) * Wq + wq;
#pragma unroll
    for (int j = 0; j < Kq; ++j) {
        float4 o0 = {acc[j][0], acc[j][1], acc[j][2], acc[j][3]};
        float4 o1 = {acc[j][4], acc[j][5], acc[j][6], acc[j][7]};
        *(float4*)(out + obase)     = o0;
        *(float4*)(out + obase + 4) = o1;
        obase += (size_t)CS;
    }
}

extern "C" void kernel_launch(void* const* d_in, const int* in_sizes, int n_in,
                              void* d_out, int out_size, void* d_ws, size_t ws_size,
                              hipStream_t stream) {
    const float* x = (const float*)d_in[0];
    const float* y = (const float*)d_in[1];
    float* out = (float*)d_out;

    // zero pad-source region (invalid/pad chunks aim here, stride 0)
    hipMemsetAsync(d_ws, 0, 256, stream);

    dim3 grid(Bq * 32 * 4);   // 1024 tiles: 8 b x 32 h x 4 w
    dim3 block(NTHR);
    hipLaunchKernelGGL(corr7_kernel, grid, block, 0, stream,
                       x, y, out, (const float*)d_ws);
}

// Round 12
// 337.502 us; speedup vs baseline: 1.1636x; 1.0007x over previous
//
#include <hip/hip_runtime.h>

// CorrNeigh: out[b, i*7+j, h, w] = sum_c x[b,c,h,w] * y[b,c,h+i-3,w+j-3]
// B=8 C=128 H=W=256, K=7, PAD=3, fp32.
//
// Round 11: LDS-pipe diet + register-demand diet on the R9 ring (best: 309us).
//  - x NO LONGER staged in LDS: each lane loads its x octet from global
//    (L1 serves the 7x dy-wave reuse). LDS reads/wave-channel: 6 -> 4 b128
//    (-33% on the binding pipe); slot = y-only 4704B; ring 28KB -> 4 blk/CU.
//  - vmem ISSUE ORDER: x loads at iteration top BEFORE the dma16s. vmcnt
//    retires in order, so consuming x only forces retirement of PREVIOUS
//    iterations' DMAs (= the vmcnt(2) semantics we want). x after the DMAs
//    would chain each iteration's FMAs to its own prefetch.
//  - Everything else proven in R8/R9: 6-slot ring, 2ch/barrier, vmcnt(2)
//    steady wait, pitch-84 y rows (uniform 8 words/bank for b128), pad via
//    zbuf pointer-redirect (stride 0), XCD-chunked swizzle, waves_per_eu(3,4).
// Ring safety (unchanged from R9): slot overwritten at iter k was read at
// iter k-1; reads drained by lgkmcnt(0)+barrier before the DMA issues; each
// producer wave waits ITS vmcnt before the barrier, so post-barrier all
// slot chunks have landed.

#define Bq 8
#define Cq 128
#define Hq 256
#define Wq 256
#define Kq 7
#define TILE_H 8
#define TILE_W 64
#define NTHR 448
#define CS (Hq * Wq)
#define SLOT 4704          // y-only: 14 rows x 21 chunks x 16B
#define NSLOT 6
#define RING (NSLOT * SLOT)
#define YPITCH_B 336       // 84 floats

typedef const __attribute__((address_space(1))) void* gptr_t;
typedef __attribute__((address_space(3))) void* lptr_t;

__device__ __forceinline__ void dma16(const float* g, char* l) {
    __builtin_amdgcn_global_load_lds((gptr_t)g, (lptr_t)l, 16, 0, 0);
}

__global__ __launch_bounds__(NTHR)
__attribute__((amdgpu_waves_per_eu(3, 4)))
void corr7_kernel(const float* __restrict__ x, const float* __restrict__ y,
                  float* __restrict__ out, const float* __restrict__ zbuf)
{
    __shared__ __align__(16) char smem[RING];

    const int t    = threadIdx.x;
    const int wave = t >> 6;        // dy index (0..6)
    const int lane = t & 63;
    const int lw   = lane & 7;      // w-octet
    const int lr   = lane >> 3;     // row in tile (0..7)

    // XCD-chunked swizzle: XCD k gets tiles [k*128,(k+1)*128) = one image
    int bid = (int)blockIdx.x;
    bid = (bid & 7) * 128 + (bid >> 3);
    const int tw = bid & 3;
    const int th = (bid >> 2) & 31;
    const int b  = bid >> 7;

    const int h0 = th * TILE_H;
    const int w0 = tw * TILE_W;
    const int wq = w0 + 8 * lw;

    const size_t base = (size_t)b * Cq * CS;

    // ---- staging role: threads 0..293 DMA one 16B y-chunk per channel ----
    const bool prod = (t < 294);
    const float* src;
    unsigned sstep;
    {
        const int r = t / 21, j = t - 21 * r;   // row 0..13, chunk 0..20
        const int gy = h0 + r - 3;
        const int gx = w0 - 8 + 4 * j;          // chunk covers gx..gx+3
        const bool v = prod && (j < 20) && ((unsigned)gy < (unsigned)Hq) &&
                       (gx >= 0) && (gx + 3 < Wq);
        src   = v ? (y + base + (size_t)gy * Wq + gx) : zbuf;
        sstep = v ? (unsigned)CS : 0u;
    }

    // ---- compute-role offsets ----
    // y window: row R=lr+wave, floats 8lw+4 .. 8lw+19 (window = idx 1..14)
    const int yb = (lr + wave) * YPITCH_B + 32 * lw + 16;
    const float* px = x + base + (size_t)(h0 + lr) * Wq + wq;

    float acc[Kq][8];
#pragma unroll
    for (int j = 0; j < Kq; ++j)
#pragma unroll
        for (int r = 0; r < 8; ++r) acc[j][r] = 0.f;

#define COMPUTE(OFF, X0, X1) {                                            \
    const char* sr = (const char*)smem + (OFF);                           \
    const float4 q0 = *(const float4*)(sr + yb);                          \
    const float4 q1 = *(const float4*)(sr + yb + 16);                     \
    const float4 q2 = *(const float4*)(sr + yb + 32);                     \
    const float4 q3 = *(const float4*)(sr + yb + 48);                     \
    float yf[16];                                                         \
    *(float4*)(yf)      = q0;  *(float4*)(yf + 4)  = q1;                  \
    *(float4*)(yf + 8)  = q2;  *(float4*)(yf + 12) = q3;                  \
    float xv[8];                                                          \
    *(float4*)(xv)      = X0;  *(float4*)(xv + 4)  = X1;                  \
    _Pragma("unroll")                                                     \
    for (int j = 0; j < Kq; ++j)                                          \
        _Pragma("unroll")                                                 \
        for (int r = 0; r < 8; ++r)                                       \
            acc[j][r] = fmaf(xv[r], yf[1 + j + r], acc[j][r]);            \
}

    // prologue: DMA channels 0..3 into slots 0..3
#pragma unroll
    for (int c = 0; c < 4; ++c) {
        if (prod) { dma16(src, smem + c * SLOT + t * 16); src += sstep; }
    }

    unsigned rd = 0;
    unsigned wr = 4u * SLOT;
    // steady: iter k computes ch 2k,2k+1; issues ch 2k+4,2k+5.
#pragma unroll 1
    for (int k = 0; k < 62; ++k) {
        asm volatile("s_waitcnt vmcnt(2) lgkmcnt(0)" ::: "memory");
        __builtin_amdgcn_s_barrier();
        // x octets for ch 2k (A) and 2k+1 (B) — issued BEFORE the DMAs
        const float4 xa0 = *(const float4*)(px);
        const float4 xa1 = *(const float4*)(px + 4);
        const float4 xb0 = *(const float4*)(px + CS);
        const float4 xb1 = *(const float4*)(px + CS + 4);
        px += 2 * CS;
        asm volatile("" ::: "memory");       // keep x-issue above DMA-issue
        if (prod) { dma16(src, smem + wr + t * 16); src += sstep; }
        wr += SLOT; if (wr == RING) wr = 0;
        if (prod) { dma16(src, smem + wr + t * 16); src += sstep; }
        wr += SLOT; if (wr == RING) wr = 0;
        COMPUTE(rd, xa0, xa1)
        rd += SLOT; if (rd == RING) rd = 0;
        COMPUTE(rd, xb0, xb1)
        rd += SLOT; if (rd == RING) rd = 0;
    }
    // drain: ch 124..127
    {
        asm volatile("s_waitcnt vmcnt(2) lgkmcnt(0)" ::: "memory");
        __builtin_amdgcn_s_barrier();
        const float4 xa0 = *(const float4*)(px);
        const float4 xa1 = *(const float4*)(px + 4);
        const float4 xb0 = *(const float4*)(px + CS);
        const float4 xb1 = *(const float4*)(px + CS + 4);
        px += 2 * CS;
        COMPUTE(rd, xa0, xa1)
        rd += SLOT; if (rd == RING) rd = 0;
        COMPUTE(rd, xb0, xb1)
        rd += SLOT; if (rd == RING) rd = 0;
    }
    {
        asm volatile("s_waitcnt vmcnt(0) lgkmcnt(0)" ::: "memory");
        __builtin_amdgcn_s_barrier();
        const float4 xa0 = *(const float4*)(px);
        const float4 xa1 = *(const float4*)(px + 4);
        const float4 xb0 = *(const float4*)(px + CS);
        const float4 xb1 = *(const float4*)(px + CS + 4);
        COMPUTE(rd, xa0, xa1)
        rd += SLOT; if (rd == RING) rd = 0;
        COMPUTE(rd, xb0, xb1)
    }
#undef COMPUTE

    // epilogue: wave writes k-planes wave*7 .. wave*7+6 (one octet each)
    size_t obase = (((size_t)b * (Kq * Kq) + (size_t)wave * Kq) * Hq
                    + (h0 + lr)) * Wq + wq;
#pragma unroll
    for (int j = 0; j < Kq; ++j) {
        float4 o0 = {acc[j][0], acc[j][1], acc[j][2], acc[j][3]};
        float4 o1 = {acc[j][4], acc[j][5], acc[j][6], acc[j][7]};
        *(float4*)(out + obase)     = o0;
        *(float4*)(out + obase + 4) = o1;
        obase += (size_t)CS;
    }
}

extern "C" void kernel_launch(void* const* d_in, const int* in_sizes, int n_in,
                              void* d_out, int out_size, void* d_ws, size_t ws_size,
                              hipStream_t stream) {
    const float* x = (const float*)d_in[0];
    const float* y = (const float*)d_in[1];
    float* out = (float*)d_out;

    // zero pad-source region (invalid/pad chunks aim here, stride 0)
    hipMemsetAsync(d_ws, 0, 256, stream);

    dim3 grid(Bq * 32 * 4);   // 1024 tiles: 8 b x 32 h x 4 w
    dim3 block(NTHR);
    hipLaunchKernelGGL(corr7_kernel, grid, block, 0, stream,
                       x, y, out, (const float*)d_ws);
}

// Round 13
// 335.595 us; speedup vs baseline: 1.1702x; 1.0057x over previous
//
#include <hip/hip_runtime.h>

// CorrNeigh: out[b, i*7+j, h, w] = sum_c x[b,c,h,w] * y[b,c,h+i-3,w+j-3]
// B=8 C=128 H=W=256, K=7, PAD=3, fp32.
//
// Round 11: LDS-pipe diet + register-demand diet on the R9 ring (best: 309us).
//  - x NO LONGER staged in LDS: each lane loads its x octet from global
//    (L1 serves the 7x dy-wave reuse). LDS reads/wave-channel: 6 -> 4 b128
//    (-33% on the binding pipe); slot = y-only 4704B; ring 28KB -> 4 blk/CU.
//  - vmem ISSUE ORDER: x loads at iteration top BEFORE the dma16s. vmcnt
//    retires in order, so consuming x only forces retirement of PREVIOUS
//    iterations' DMAs (= the vmcnt(2) semantics we want). x after the DMAs
//    would chain each iteration's FMAs to its own prefetch.
//  - Everything else proven in R8/R9: 6-slot ring, 2ch/barrier, vmcnt(2)
//    steady wait, pitch-84 y rows (uniform 8 words/bank for b128), pad via
//    zbuf pointer-redirect (stride 0), XCD-chunked swizzle, waves_per_eu(3,4).
// Ring safety (unchanged from R9): slot overwritten at iter k was read at
// iter k-1; reads drained by lgkmcnt(0)+barrier before the DMA issues; each
// producer wave waits ITS vmcnt before the barrier, so post-barrier all
// slot chunks have landed.

#define Bq 8
#define Cq 128
#define Hq 256
#define Wq 256
#define Kq 7
#define TILE_H 8
#define TILE_W 64
#define NTHR 448
#define CS (Hq * Wq)
#define SLOT 4704          // y-only: 14 rows x 21 chunks x 16B
#define NSLOT 6
#define RING (NSLOT * SLOT)
#define YPITCH_B 336       // 84 floats

typedef const __attribute__((address_space(1))) void* gptr_t;
typedef __attribute__((address_space(3))) void* lptr_t;

__device__ __forceinline__ void dma16(const float* g, char* l) {
    __builtin_amdgcn_global_load_lds((gptr_t)g, (lptr_t)l, 16, 0, 0);
}

__global__ __launch_bounds__(NTHR)
__attribute__((amdgpu_waves_per_eu(3, 4)))
void corr7_kernel(const float* __restrict__ x, const float* __restrict__ y,
                  float* __restrict__ out, const float* __restrict__ zbuf)
{
    __shared__ __align__(16) char smem[RING];

    const int t    = threadIdx.x;
    const int wave = t >> 6;        // dy index (0..6)
    const int lane = t & 63;
    const int lw   = lane & 7;      // w-octet
    const int lr   = lane >> 3;     // row in tile (0..7)

    // XCD-chunked swizzle: XCD k gets tiles [k*128,(k+1)*128) = one image
    int bid = (int)blockIdx.x;
    bid = (bid & 7) * 128 + (bid >> 3);
    const int tw = bid & 3;
    const int th = (bid >> 2) & 31;
    const int b  = bid >> 7;

    const int h0 = th * TILE_H;
    const int w0 = tw * TILE_W;
    const int wq = w0 + 8 * lw;

    const size_t base = (size_t)b * Cq * CS;

    // ---- staging role: threads 0..293 DMA one 16B y-chunk per channel ----
    const bool prod = (t < 294);
    const float* src;
    unsigned sstep;
    {
        const int r = t / 21, j = t - 21 * r;   // row 0..13, chunk 0..20
        const int gy = h0 + r - 3;
        const int gx = w0 - 8 + 4 * j;          // chunk covers gx..gx+3
        const bool v = prod && (j < 20) && ((unsigned)gy < (unsigned)Hq) &&
                       (gx >= 0) && (gx + 3 < Wq);
        src   = v ? (y + base + (size_t)gy * Wq + gx) : zbuf;
        sstep = v ? (unsigned)CS : 0u;
    }

    // ---- compute-role offsets ----
    // y window: row R=lr+wave, floats 8lw+4 .. 8lw+19 (window = idx 1..14)
    const int yb = (lr + wave) * YPITCH_B + 32 * lw + 16;
    const float* px = x + base + (size_t)(h0 + lr) * Wq + wq;

    float acc[Kq][8];
#pragma unroll
    for (int j = 0; j < Kq; ++j)
#pragma unroll
        for (int r = 0; r < 8; ++r) acc[j][r] = 0.f;

#define COMPUTE(OFF, X0, X1) {                                            \
    const char* sr = (const char*)smem + (OFF);                           \
    const float4 q0 = *(const float4*)(sr + yb);                          \
    const float4 q1 = *(const float4*)(sr + yb + 16);                     \
    const float4 q2 = *(const float4*)(sr + yb + 32);                     \
    const float4 q3 = *(const float4*)(sr + yb + 48);                     \
    float yf[16];                                                         \
    *(float4*)(yf)      = q0;  *(float4*)(yf + 4)  = q1;                  \
    *(float4*)(yf + 8)  = q2;  *(float4*)(yf + 12) = q3;                  \
    float xv[8];                                                          \
    *(float4*)(xv)      = X0;  *(float4*)(xv + 4)  = X1;                  \
    _Pragma("unroll")                                                     \
    for (int j = 0; j < Kq; ++j)                                          \
        _Pragma("unroll")                                                 \
        for (int r = 0; r < 8; ++r)                                       \
            acc[j][r] = fmaf(xv[r], yf[1 + j + r], acc[j][r]);            \
}

    // prologue: DMA channels 0..3 into slots 0..3
#pragma unroll
    for (int c = 0; c < 4; ++c) {
        if (prod) { dma16(src, smem + c * SLOT + t * 16); src += sstep; }
    }

    unsigned rd = 0;
    unsigned wr = 4u * SLOT;
    // steady: iter k computes ch 2k,2k+1; issues ch 2k+4,2k+5.
#pragma unroll 1
    for (int k = 0; k < 62; ++k) {
        asm volatile("s_waitcnt vmcnt(2) lgkmcnt(0)" ::: "memory");
        __builtin_amdgcn_s_barrier();
        // x octets for ch 2k (A) and 2k+1 (B) — issued BEFORE the DMAs
        const float4 xa0 = *(const float4*)(px);
        const float4 xa1 = *(const float4*)(px + 4);
        const float4 xb0 = *(const float4*)(px + CS);
        const float4 xb1 = *(const float4*)(px + CS + 4);
        px += 2 * CS;
        asm volatile("" ::: "memory");       // keep x-issue above DMA-issue
        if (prod) { dma16(src, smem + wr + t * 16); src += sstep; }
        wr += SLOT; if (wr == RING) wr = 0;
        if (prod) { dma16(src, smem + wr + t * 16); src += sstep; }
        wr += SLOT; if (wr == RING) wr = 0;
        COMPUTE(rd, xa0, xa1)
        rd += SLOT; if (rd == RING) rd = 0;
        COMPUTE(rd, xb0, xb1)
        rd += SLOT; if (rd == RING) rd = 0;
    }
    // drain: ch 124..127
    {
        asm volatile("s_waitcnt vmcnt(2) lgkmcnt(0)" ::: "memory");
        __builtin_amdgcn_s_barrier();
        const float4 xa0 = *(const float4*)(px);
        const float4 xa1 = *(const float4*)(px + 4);
        const float4 xb0 = *(const float4*)(px + CS);
        const float4 xb1 = *(const float4*)(px + CS + 4);
        px += 2 * CS;
        COMPUTE(rd, xa0, xa1)
        rd += SLOT; if (rd == RING) rd = 0;
        COMPUTE(rd, xb0, xb1)
        rd += SLOT; if (rd == RING) rd = 0;
    }
    {
        asm volatile("s_waitcnt vmcnt(0) lgkmcnt(0)" ::: "memory");
        __builtin_amdgcn_s_barrier();
        const float4 xa0 = *(const float4*)(px);
        const float4 xa1 = *(const float4*)(px + 4);
        const float4 xb0 = *(const float4*)(px + CS);
        const float4 xb1 = *(const float4*)(px + CS + 4);
        COMPUTE(rd, xa0, xa1)
        rd += SLOT; if (rd == RING) rd = 0;
        COMPUTE(rd, xb0, xb1)
    }
#undef COMPUTE

    // epilogue: wave writes k-planes wave*7 .. wave*7+6 (one octet each)
    size_t obase = (((size_t)b * (Kq * Kq) + (size_t)wave * Kq) * Hq
                    + (h0 + lr)) * Wq + wq;
#pragma unroll
    for (int j = 0; j < Kq; ++j) {
        float4 o0 = {acc[j][0], acc[j][1], acc[j][2], acc[j][3]};
        float4 o1 = {acc[j][4], acc[j][5], acc[j][6], acc[j][7]};
        *(float4*)(out + obase)     = o0;
        *(float4*)(out + obase + 4) = o1;
        obase += (size_t)CS;
    }
}

extern "C" void kernel_launch(void* const* d_in, const int* in_sizes, int n_in,
                              void* d_out, int out_size, void* d_ws, size_t ws_size,
                              hipStream_t stream) {
    const float* x = (const float*)d_in[0];
    const float* y = (const float*)d_in[1];
    float* out = (float*)d_out;

    // zero pad-source region (invalid/pad chunks aim here, stride 0)
    hipMemsetAsync(d_ws, 0, 256, stream);

    dim3 grid(Bq * 32 * 4);   // 1024 tiles: 8 b x 32 h x 4 w
    dim3 block(NTHR);
    hipLaunchKernelGGL(corr7_kernel, grid, block, 0, stream,
                       x, y, out, (const float*)d_ws);
}

// Round 14
// 332.662 us; speedup vs baseline: 1.1806x; 1.0088x over previous
//
#include <hip/hip_runtime.h>

// CorrNeigh: out[b, i*7+j, h, w] = sum_c x[b,c,h,w] * y[b,c,h+i-3,w+j-3]
// B=8 C=128 H=W=256, K=7, PAD=3, fp32.
//
// Round 11: LDS-pipe diet + register-demand diet on the R9 ring (best: 309us).
//  - x NO LONGER staged in LDS: each lane loads its x octet from global
//    (L1 serves the 7x dy-wave reuse). LDS reads/wave-channel: 6 -> 4 b128
//    (-33% on the binding pipe); slot = y-only 4704B; ring 28KB -> 4 blk/CU.
//  - vmem ISSUE ORDER: x loads at iteration top BEFORE the dma16s. vmcnt
//    retires in order, so consuming x only forces retirement of PREVIOUS
//    iterations' DMAs (= the vmcnt(2) semantics we want). x after the DMAs
//    would chain each iteration's FMAs to its own prefetch.
//  - Everything else proven in R8/R9: 6-slot ring, 2ch/barrier, vmcnt(2)
//    steady wait, pitch-84 y rows (uniform 8 words/bank for b128), pad via
//    zbuf pointer-redirect (stride 0), XCD-chunked swizzle, waves_per_eu(3,4).
// Ring safety (unchanged from R9): slot overwritten at iter k was read at
// iter k-1; reads drained by lgkmcnt(0)+barrier before the DMA issues; each
// producer wave waits ITS vmcnt before the barrier, so post-barrier all
// slot chunks have landed.

#define Bq 8
#define Cq 128
#define Hq 256
#define Wq 256
#define Kq 7
#define TILE_H 8
#define TILE_W 64
#define NTHR 448
#define CS (Hq * Wq)
#define SLOT 4704          // y-only: 14 rows x 21 chunks x 16B
#define NSLOT 6
#define RING (NSLOT * SLOT)
#define YPITCH_B 336       // 84 floats

typedef const __attribute__((address_space(1))) void* gptr_t;
typedef __attribute__((address_space(3))) void* lptr_t;

__device__ __forceinline__ void dma16(const float* g, char* l) {
    __builtin_amdgcn_global_load_lds((gptr_t)g, (lptr_t)l, 16, 0, 0);
}

__global__ __launch_bounds__(NTHR)
__attribute__((amdgpu_waves_per_eu(3, 4)))
void corr7_kernel(const float* __restrict__ x, const float* __restrict__ y,
                  float* __restrict__ out, const float* __restrict__ zbuf)
{
    __shared__ __align__(16) char smem[RING];

    const int t    = threadIdx.x;
    const int wave = t >> 6;        // dy index (0..6)
    const int lane = t & 63;
    const int lw   = lane & 7;      // w-octet
    const int lr   = lane >> 3;     // row in tile (0..7)

    // XCD-chunked swizzle: XCD k gets tiles [k*128,(k+1)*128) = one image
    int bid = (int)blockIdx.x;
    bid = (bid & 7) * 128 + (bid >> 3);
    const int tw = bid & 3;
    const int th = (bid >> 2) & 31;
    const int b  = bid >> 7;

    const int h0 = th * TILE_H;
    const int w0 = tw * TILE_W;
    const int wq = w0 + 8 * lw;

    const size_t base = (size_t)b * Cq * CS;

    // ---- staging role: threads 0..293 DMA one 16B y-chunk per channel ----
    const bool prod = (t < 294);
    const float* src;
    unsigned sstep;
    {
        const int r = t / 21, j = t - 21 * r;   // row 0..13, chunk 0..20
        const int gy = h0 + r - 3;
        const int gx = w0 - 8 + 4 * j;          // chunk covers gx..gx+3
        const bool v = prod && (j < 20) && ((unsigned)gy < (unsigned)Hq) &&
                       (gx >= 0) && (gx + 3 < Wq);
        src   = v ? (y + base + (size_t)gy * Wq + gx) : zbuf;
        sstep = v ? (unsigned)CS : 0u;
    }

    // ---- compute-role offsets ----
    // y window: row R=lr+wave, floats 8lw+4 .. 8lw+19 (window = idx 1..14)
    const int yb = (lr + wave) * YPITCH_B + 32 * lw + 16;
    const float* px = x + base + (size_t)(h0 + lr) * Wq + wq;

    float acc[Kq][8];
#pragma unroll
    for (int j = 0; j < Kq; ++j)
#pragma unroll
        for (int r = 0; r < 8; ++r) acc[j][r] = 0.f;

#define COMPUTE(OFF, X0, X1) {                                            \
    const char* sr = (const char*)smem + (OFF);                           \
    const float4 q0 = *(const float4*)(sr + yb);                          \
    const float4 q1 = *(const float4*)(sr + yb + 16);                     \
    const float4 q2 = *(const float4*)(sr + yb + 32);                     \
    const float4 q3 = *(const float4*)(sr + yb + 48);                     \
    float yf[16];                                                         \
    *(float4*)(yf)      = q0;  *(float4*)(yf + 4)  = q1;                  \
    *(float4*)(yf + 8)  = q2;  *(float4*)(yf + 12) = q3;                  \
    float xv[8];                                                          \
    *(float4*)(xv)      = X0;  *(float4*)(xv + 4)  = X1;                  \
    _Pragma("unroll")                                                     \
    for (int j = 0; j < Kq; ++j)                                          \
        _Pragma("unroll")                                                 \
        for (int r = 0; r < 8; ++r)                                       \
            acc[j][r] = fmaf(xv[r], yf[1 + j + r], acc[j][r]);            \
}

    // prologue: DMA channels 0..3 into slots 0..3
#pragma unroll
    for (int c = 0; c < 4; ++c) {
        if (prod) { dma16(src, smem + c * SLOT + t * 16); src += sstep; }
    }

    unsigned rd = 0;
    unsigned wr = 4u * SLOT;
    // steady: iter k computes ch 2k,2k+1; issues ch 2k+4,2k+5.
#pragma unroll 1
    for (int k = 0; k < 62; ++k) {
        asm volatile("s_waitcnt vmcnt(2) lgkmcnt(0)" ::: "memory");
        __builtin_amdgcn_s_barrier();
        // x octets for ch 2k (A) and 2k+1 (B) — issued BEFORE the DMAs
        const float4 xa0 = *(const float4*)(px);
        const float4 xa1 = *(const float4*)(px + 4);
        const float4 xb0 = *(const float4*)(px + CS);
        const float4 xb1 = *(const float4*)(px + CS + 4);
        px += 2 * CS;
        asm volatile("" ::: "memory");       // keep x-issue above DMA-issue
        if (prod) { dma16(src, smem + wr + t * 16); src += sstep; }
        wr += SLOT; if (wr == RING) wr = 0;
        if (prod) { dma16(src, smem + wr + t * 16); src += sstep; }
        wr += SLOT; if (wr == RING) wr = 0;
        COMPUTE(rd, xa0, xa1)
        rd += SLOT; if (rd == RING) rd = 0;
        COMPUTE(rd, xb0, xb1)
        rd += SLOT; if (rd == RING) rd = 0;
    }
    // drain: ch 124..127
    {
        asm volatile("s_waitcnt vmcnt(2) lgkmcnt(0)" ::: "memory");
        __builtin_amdgcn_s_barrier();
        const float4 xa0 = *(const float4*)(px);
        const float4 xa1 = *(const float4*)(px + 4);
        const float4 xb0 = *(const float4*)(px + CS);
        const float4 xb1 = *(const float4*)(px + CS + 4);
        px += 2 * CS;
        COMPUTE(rd, xa0, xa1)
        rd += SLOT; if (rd == RING) rd = 0;
        COMPUTE(rd, xb0, xb1)
        rd += SLOT; if (rd == RING) rd = 0;
    }
    {
        asm volatile("s_waitcnt vmcnt(0) lgkmcnt(0)" ::: "memory");
        __builtin_amdgcn_s_barrier();
        const float4 xa0 = *(const float4*)(px);
        const float4 xa1 = *(const float4*)(px + 4);
        const float4 xb0 = *(const float4*)(px + CS);
        const float4 xb1 = *(const float4*)(px + CS + 4);
        COMPUTE(rd, xa0, xa1)
        rd += SLOT; if (rd == RING) rd = 0;
        COMPUTE(rd, xb0, xb1)
    }
#undef COMPUTE

    // epilogue: wave writes k-planes wave*7 .. wave*7+6 (one octet each)
    size_t obase = (((size_t)b * (Kq * Kq) + (size_t)wave * Kq) * Hq
                    + (h0 + lr)) * Wq + wq;
#pragma unroll
    for (int j = 0; j < Kq; ++j) {
        float4 o0 = {acc[j][0], acc[j][1], acc[j][2], acc[j][3]};
        float4 o1 = {acc[j][4], acc[j][5], acc[j][6], acc[j][7]};
        *(float4*)(out + obase)     = o0;
        *(float4*)(out + obase + 4) = o1;
        obase += (size_t)CS;
    }
}

extern "C" void kernel_launch(void* const* d_in, const int* in_sizes, int n_in,
                              void* d_out, int out_size, void* d_ws, size_t ws_size,
                              hipStream_t stream) {
    const float* x = (const float*)d_in[0];
    const float* y = (const float*)d_in[1];
    float* out = (float*)d_out;

    // zero pad-source region (invalid/pad chunks aim here, stride 0)
    hipMemsetAsync(d_ws, 0, 256, stream);

    dim3 grid(Bq * 32 * 4);   // 1024 tiles: 8 b x 32 h x 4 w
    dim3 block(NTHR);
    hipLaunchKernelGGL(corr7_kernel, grid, block, 0, stream,
                       x, y, out, (const float*)d_ws);
}